// Round 12
// baseline (90.663 us; speedup 1.0000x reference)
//
#include <hip/hip_runtime.h>
#include <float.h>

// Chamfer distance, fp32, N=M=16384 — MFMA 32x32, 4 A-frags/wave (R12).
//
// d(q,t) = u.t + |t|^2 + |q|^2, u=-2q, K=4 dot -> matrix cores via 2-level
// bf16 split, full product expansion packed in K=14 of 16 (absmax 0.0
// verified R7/R8/R10/R11):
//   k:      0..2     3..5     6..7+8   9..11    12 13
//   A:    uh(xyz)  ul(xyz)  uh(xyz)  ul(xyz)    1  1
//   B:    th(xyz)  th(xyz)  tl(xyz)  tl(xyz)   wh wl
//
// R11 post-mortem: launch-merge + depth-1 prefetch NULL (82.9 vs 81.7).
// Null ledger on this structure: occupancy x2, min3 pairing, prefetch,
// launch count. cd_main bounded <39.7us by rocprof (fills at 40 outrank
// it); est ~34 vs overlapped floor ~8 (MFMA 6.9 / VALU 3.4 / L2 7.8 —
// 512 blocks x 512KB = 268MB L2 reads). Untested suspects: L2 traffic +
// L2 latency at depth-1 pipelining (L1 is thrashed: 16 waves x 64KB
// distinct streams through 32KB L1). R12: QPB 64->128 via 4 A-frags/wave
// (B-load amortized over 4 MFMAs, L2 traffic halved to 134MB), blocks
// 512->256 (1/CU), launch_bounds(512,2) -> 256-VGPR cap so the ~130-160
// live set CANNOT spill (R9 inverted: buy reg headroom, not occupancy —
// occupancy was proven null) and the compiler can deep-pipeline the
// in-loop loads with the spare ~100 regs.
//
// Layouts (guide §3, m74/m101-verified for 32x32):
//   A (32r x 16k): row = lane&31, k = 8*(lane>>5)+j
//   B (16k x 32c): col = lane&31, k = 8*(lane>>5)+j
//   D: col = lane&31, row = (reg&3) + 8*(reg>>2) + 4*(lane>>5)

#define NPTS 16384
constexpr int QPB   = 128;                // queries per block (4 A-frags/wave)
constexpr int NAF   = 4;                  // A-frags per wave
constexpr int NBLK  = NPTS / QPB;         // 128 blocks per direction
constexpr int NFRAG = NPTS / 32;          // 512 B-frags per point set
constexpr int FPW   = NFRAG / 8;          // 64 frags swept per wave
constexpr int SET_SHORTS = NFRAG * 512;   // 262144 shorts = 512 KB per set

typedef float f32x16 __attribute__((ext_vector_type(16)));
typedef short bf16x8 __attribute__((ext_vector_type(8)));

__device__ inline ushort bf16rne(float f) {
    uint u = __float_as_uint(f);
    u += 0x7fff + ((u >> 16) & 1);        // round-to-nearest-even
    return (ushort)(u >> 16);
}
__device__ inline float bf2f(ushort h) { return __uint_as_float(((uint)h) << 16); }

// Split both point sets into B-fragment layout: bt[set][frag][lane][8 bf16].
// Also zeroes the output accumulator for cd_main's atomic finish.
__global__ __launch_bounds__(512) void cd_prep(const float* __restrict__ gt,
                                               const float* __restrict__ gen,
                                               short* __restrict__ bt,
                                               float* __restrict__ out) {
    if (blockIdx.x == 0 && threadIdx.x == 0) out[0] = 0.0f;

    const int t   = blockIdx.x * 512 + threadIdx.x;   // 0..65535
    const int set = t >> 15;                          // 0: gt, 1: gen
    const int rem = t & 32767;
    const int h   = rem >> 14;                        // k-group 0/1
    const int p   = rem & (NPTS - 1);                 // point index
    const float* __restrict__ src = set ? gen : gt;

    const float x = src[3 * p + 0], y = src[3 * p + 1], z = src[3 * p + 2];
    const ushort hx = bf16rne(x), hy = bf16rne(y), hz = bf16rne(z);
    const ushort lx = bf16rne(x - bf2f(hx));
    const ushort ly = bf16rne(y - bf2f(hy));
    const ushort lz = bf16rne(z - bf2f(hz));
    const float w = fmaf(x, x, fmaf(y, y, z * z));
    const ushort wh = bf16rne(w), wl = bf16rne(w - bf2f(wh));

    bf16x8 v;
    if (h == 0)
        v = (bf16x8){(short)hx, (short)hy, (short)hz, (short)hx,
                     (short)hy, (short)hz, (short)lx, (short)ly};
    else
        v = (bf16x8){(short)lz, (short)lx, (short)ly, (short)lz,
                     (short)wh, (short)wl, (short)0, (short)0};
    *(bf16x8*)(bt + set * SET_SHORTS + (p >> 5) * 512 + (h * 32 + (p & 31)) * 8) = v;
}

__global__ __launch_bounds__(512, 2) void cd_main(const float* __restrict__ gt,
                                                  const float* __restrict__ gen,
                                                  const short* __restrict__ bt,
                                                  float* __restrict__ out) {
    const int dir = blockIdx.y;                    // 0: gt->gen, 1: gen->gt
    const float* __restrict__ Q = dir ? gen : gt;
    const short* __restrict__ BT = bt + (dir ? 0 : SET_SHORTS);  // opposite set

    __shared__ float wm[8][QPB];

    const int tid  = threadIdx.x;
    const int lane = tid & 63;
    const int wave = __builtin_amdgcn_readfirstlane(tid >> 6);

    // ---- 4 A-frags per wave (all waves share the same 128 queries). ----
    const int arow = lane & 31, kg = lane >> 5;
    const int qbase = blockIdx.x * QPB;
    bf16x8 a[NAF];
    #pragma unroll
    for (int f = 0; f < NAF; ++f) {
        const int q = qbase + f * 32 + arow;
        const float x = Q[3 * q + 0], y = Q[3 * q + 1], z = Q[3 * q + 2];
        const float ux = -2.f * x, uy = -2.f * y, uz = -2.f * z;
        const ushort hx = bf16rne(ux), hy = bf16rne(uy), hz = bf16rne(uz);
        const ushort lx = bf16rne(ux - bf2f(hx));
        const ushort ly = bf16rne(uy - bf2f(hy));
        const ushort lz = bf16rne(uz - bf2f(hz));
        if (kg == 0)
            a[f] = (bf16x8){(short)hx, (short)hy, (short)hz, (short)lx,
                            (short)ly, (short)lz, (short)hx, (short)hy};
        else
            a[f] = (bf16x8){(short)hz, (short)lx, (short)ly, (short)lz,
                            (short)0x3f80, (short)0x3f80, (short)0, (short)0};
    }

    f32x16 mm[NAF];
    #pragma unroll
    for (int f = 0; f < NAF; ++f) mm[f] = (f32x16)(FLT_MAX);
    const f32x16 zc = (f32x16)(0.f);

    // ---- Sweep this wave's 64 B-frags from L2, 2 per step, each pair
    //      amortized over 4 A-frags (8 MFMA / 2 loads), min3-merged. ----
    const short* rb = BT + (wave * FPW) * 512 + lane * 8;
    for (int f2 = 0; f2 < FPW; f2 += 2) {
        const bf16x8 b0 = *(const bf16x8*)(rb + f2 * 512);
        const bf16x8 b1 = *(const bf16x8*)(rb + (f2 + 1) * 512);
        #pragma unroll
        for (int f = 0; f < NAF; ++f) {
            const f32x16 d0 = __builtin_amdgcn_mfma_f32_32x32x16_bf16(a[f], b0, zc, 0, 0, 0);
            const f32x16 d1 = __builtin_amdgcn_mfma_f32_32x32x16_bf16(a[f], b1, zc, 0, 0, 0);
            #pragma unroll
            for (int i = 0; i < 16; ++i)
                mm[f][i] = fminf(fminf(d0[i], d1[i]), mm[f][i]);   // v_min3_f32
        }
    }

    // ---- Cross-lane min over the 32 target-cols of each D row. ----
    #pragma unroll
    for (int f = 0; f < NAF; ++f) {
        #pragma unroll
        for (int i = 0; i < 16; ++i) {
            float v = mm[f][i];
            #pragma unroll
            for (int off = 1; off <= 16; off <<= 1)
                v = fminf(v, __shfl_xor(v, off, 64));
            const int row = (i & 3) + 8 * (i >> 2) + 4 * kg;
            if ((lane & 31) == 0) wm[wave][f * 32 + row] = v;
        }
    }
    __syncthreads();

    // ---- Merge the 8 wave-slices, add |q|^2, sum, one atomic per wave. ----
    if (tid < QPB) {
        float v = wm[0][tid];
        #pragma unroll
        for (int w = 1; w < 8; ++w) v = fminf(v, wm[w][tid]);
        const int q = qbase + tid;
        const float x = Q[3 * q + 0], y = Q[3 * q + 1], z = Q[3 * q + 2];
        v += fmaf(x, x, fmaf(y, y, z * z));
        #pragma unroll
        for (int off = 32; off > 0; off >>= 1) v += __shfl_down(v, off, 64);
        if ((tid & 63) == 0) atomicAdd(out, v * (1.0f / (float)NPTS));
    }
}

extern "C" void kernel_launch(void* const* d_in, const int* in_sizes, int n_in,
                              void* d_out, int out_size, void* d_ws, size_t ws_size,
                              hipStream_t stream) {
    const float* gt  = (const float*)d_in[0];
    const float* gen = (const float*)d_in[1];
    short* bt        = (short*)d_ws;               // 2 x 512 KB B-frags
    float* out       = (float*)d_out;

    cd_prep<<<128, 512, 0, stream>>>(gt, gen, bt, out);
    dim3 grid(NBLK, 2);                            // 128 x 2 = 256 blocks
    cd_main<<<grid, 512, 0, stream>>>(gt, gen, bt, out);
}

// Round 14
// 82.380 us; speedup vs baseline: 1.1005x; 1.1005x over previous
//
#include <hip/hip_runtime.h>
#include <float.h>

// Chamfer distance, fp32, N=M=16384 — MFMA 32x32, depth-2 pipeline (R13
// resubmit; R13 bench was an infra failure — container died, no data).
//
// d(q,t) = u.t + |t|^2 + |q|^2, u=-2q, K=4 dot -> matrix cores via 2-level
// bf16 split, full product expansion packed in K=14 of 16 (absmax 0.0
// verified R7-R12):
//   k:      0..2     3..5     6..7+8   9..11    12 13
//   A:    uh(xyz)  ul(xyz)  uh(xyz)  ul(xyz)    1  1
//   B:    th(xyz)  th(xyz)  tl(xyz)  tl(xyz)   wh wl
//
// R12 post-mortem: halving L2 traffic with NAF=4 but dropping to 8 waves/CU
// REGRESSED (90.7 vs 81.7) -> latency exposure, not L2 throughput, is the
// binding constraint. Occupancy ceiling: accumulators force >=65 VGPR ->
// 16 waves/CU max (waves halve at the 64-reg step) — TLP is maxed, so the
// lever is ILP. Per-iter budget: ~160 cyc measured vs ~60 issue -> ~1
// exposed L2 round trip/iter. Depth-1 prefetch (R11) was null because the
// load led its use by <1 iter; R13 runs DEPTH-2 (load leads by ~450 cyc).
// R9's depth-2 spill came from unroll-2 + duplicated tail (live d-sets
// doubled), not the pipeline: here, named-var 3-buffer rotation, no unroll
// pragmas, wrap via &(FPW-1). Live set ~106 <= 128 cap.
//
// Layouts (guide §3, m74/m101-verified for 32x32):
//   A (32r x 16k): row = lane&31, k = 8*(lane>>5)+j
//   B (16k x 32c): col = lane&31, k = 8*(lane>>5)+j
//   D: col = lane&31, row = (reg&3) + 8*(reg>>2) + 4*(lane>>5)

#define NPTS 16384
constexpr int QPB   = 64;                 // queries per block (2 A-frags)
constexpr int NBLK  = NPTS / QPB;         // 256 blocks per direction
constexpr int NFRAG = NPTS / 32;          // 512 B-frags per point set
constexpr int FPW   = NFRAG / 8;          // 64 frags swept per wave
constexpr int SET_SHORTS = NFRAG * 512;   // 262144 shorts = 512 KB per set

typedef float f32x16 __attribute__((ext_vector_type(16)));
typedef short bf16x8 __attribute__((ext_vector_type(8)));

__device__ inline ushort bf16rne(float f) {
    uint u = __float_as_uint(f);
    u += 0x7fff + ((u >> 16) & 1);        // round-to-nearest-even
    return (ushort)(u >> 16);
}
__device__ inline float bf2f(ushort h) { return __uint_as_float(((uint)h) << 16); }

// Split both point sets into B-fragment layout: bt[set][frag][lane][8 bf16].
// Also zeroes the output accumulator for cd_main's atomic finish.
__global__ __launch_bounds__(512) void cd_prep(const float* __restrict__ gt,
                                               const float* __restrict__ gen,
                                               short* __restrict__ bt,
                                               float* __restrict__ out) {
    if (blockIdx.x == 0 && threadIdx.x == 0) out[0] = 0.0f;

    const int t   = blockIdx.x * 512 + threadIdx.x;   // 0..65535
    const int set = t >> 15;                          // 0: gt, 1: gen
    const int rem = t & 32767;
    const int h   = rem >> 14;                        // k-group 0/1
    const int p   = rem & (NPTS - 1);                 // point index
    const float* __restrict__ src = set ? gen : gt;

    const float x = src[3 * p + 0], y = src[3 * p + 1], z = src[3 * p + 2];
    const ushort hx = bf16rne(x), hy = bf16rne(y), hz = bf16rne(z);
    const ushort lx = bf16rne(x - bf2f(hx));
    const ushort ly = bf16rne(y - bf2f(hy));
    const ushort lz = bf16rne(z - bf2f(hz));
    const float w = fmaf(x, x, fmaf(y, y, z * z));
    const ushort wh = bf16rne(w), wl = bf16rne(w - bf2f(wh));

    bf16x8 v;
    if (h == 0)
        v = (bf16x8){(short)hx, (short)hy, (short)hz, (short)hx,
                     (short)hy, (short)hz, (short)lx, (short)ly};
    else
        v = (bf16x8){(short)lz, (short)lx, (short)ly, (short)lz,
                     (short)wh, (short)wl, (short)0, (short)0};
    *(bf16x8*)(bt + set * SET_SHORTS + (p >> 5) * 512 + (h * 32 + (p & 31)) * 8) = v;
}

__global__ __launch_bounds__(512, 4) void cd_main(const float* __restrict__ gt,
                                                  const float* __restrict__ gen,
                                                  const short* __restrict__ bt,
                                                  float* __restrict__ out) {
    const int dir = blockIdx.y;                    // 0: gt->gen, 1: gen->gt
    const float* __restrict__ Q = dir ? gen : gt;
    const short* __restrict__ BT = bt + (dir ? 0 : SET_SHORTS);  // opposite set

    __shared__ float wm[8][QPB];

    const int tid  = threadIdx.x;
    const int lane = tid & 63;
    const int wave = __builtin_amdgcn_readfirstlane(tid >> 6);

    // ---- 2 A-frags per wave (all waves share the same 64 queries). ----
    const int arow = lane & 31, kg = lane >> 5;
    const int qbase = blockIdx.x * QPB;
    bf16x8 a[2];
    #pragma unroll
    for (int f = 0; f < 2; ++f) {
        const int q = qbase + f * 32 + arow;
        const float x = Q[3 * q + 0], y = Q[3 * q + 1], z = Q[3 * q + 2];
        const float ux = -2.f * x, uy = -2.f * y, uz = -2.f * z;
        const ushort hx = bf16rne(ux), hy = bf16rne(uy), hz = bf16rne(uz);
        const ushort lx = bf16rne(ux - bf2f(hx));
        const ushort ly = bf16rne(uy - bf2f(hy));
        const ushort lz = bf16rne(uz - bf2f(hz));
        if (kg == 0)
            a[f] = (bf16x8){(short)hx, (short)hy, (short)hz, (short)lx,
                            (short)ly, (short)lz, (short)hx, (short)hy};
        else
            a[f] = (bf16x8){(short)hz, (short)lx, (short)ly, (short)lz,
                            (short)0x3f80, (short)0x3f80, (short)0, (short)0};
    }

    f32x16 mm0 = (f32x16)(FLT_MAX), mm1 = (f32x16)(FLT_MAX);
    const f32x16 zc = (f32x16)(0.f);

    // ---- Sweep this wave's 64 B-frags, depth-2 software pipeline:
    //      3 live pairs (cur / next / next2), named vars, no unroll,
    //      wrap on the over-fetch. Loads lead their use by 2 iterations
    //      (~450 cyc) so L2 latency is fully covered. ----
    const short* rb = BT + (wave * FPW) * 512 + lane * 8;
    bf16x8 c0 = *(const bf16x8*)(rb);
    bf16x8 c1 = *(const bf16x8*)(rb + 512);
    bf16x8 p0 = *(const bf16x8*)(rb + 1024);
    bf16x8 p1 = *(const bf16x8*)(rb + 1536);
    for (int f2 = 0; f2 < FPW; f2 += 2) {
        const int nf = (f2 + 4) & (FPW - 1);       // wrap: harmless refetch
        const bf16x8 n0 = *(const bf16x8*)(rb + nf * 512);
        const bf16x8 n1 = *(const bf16x8*)(rb + (nf + 1) * 512);
        const f32x16 d00 = __builtin_amdgcn_mfma_f32_32x32x16_bf16(a[0], c0, zc, 0, 0, 0);
        const f32x16 d01 = __builtin_amdgcn_mfma_f32_32x32x16_bf16(a[0], c1, zc, 0, 0, 0);
        #pragma unroll
        for (int i = 0; i < 16; ++i)
            mm0[i] = fminf(fminf(d00[i], d01[i]), mm0[i]);   // -> v_min3_f32
        const f32x16 d10 = __builtin_amdgcn_mfma_f32_32x32x16_bf16(a[1], c0, zc, 0, 0, 0);
        const f32x16 d11 = __builtin_amdgcn_mfma_f32_32x32x16_bf16(a[1], c1, zc, 0, 0, 0);
        #pragma unroll
        for (int i = 0; i < 16; ++i)
            mm1[i] = fminf(fminf(d10[i], d11[i]), mm1[i]);
        c0 = p0; c1 = p1; p0 = n0; p1 = n1;        // rotate the 3 pairs
    }

    // ---- Cross-lane min over the 32 target-cols of each D row. ----
    #pragma unroll
    for (int i = 0; i < 16; ++i) {
        float v0 = mm0[i], v1 = mm1[i];
        #pragma unroll
        for (int off = 1; off <= 16; off <<= 1) {
            v0 = fminf(v0, __shfl_xor(v0, off, 64));
            v1 = fminf(v1, __shfl_xor(v1, off, 64));
        }
        const int row = (i & 3) + 8 * (i >> 2) + 4 * kg;
        if ((lane & 31) == 0) {
            wm[wave][row]      = v0;               // frag 0: queries qbase+row
            wm[wave][32 + row] = v1;               // frag 1: queries qbase+32+row
        }
    }
    __syncthreads();

    // ---- Merge the 8 wave-slices, add |q|^2, sum 64 queries, one atomic. ----
    if (tid < QPB) {
        float v = wm[0][tid];
        #pragma unroll
        for (int w = 1; w < 8; ++w) v = fminf(v, wm[w][tid]);
        const int q = qbase + tid;
        const float x = Q[3 * q + 0], y = Q[3 * q + 1], z = Q[3 * q + 2];
        v += fmaf(x, x, fmaf(y, y, z * z));
        #pragma unroll
        for (int off = 32; off > 0; off >>= 1) v += __shfl_down(v, off, 64);
        if (tid == 0) atomicAdd(out, v * (1.0f / (float)NPTS));
    }
}

extern "C" void kernel_launch(void* const* d_in, const int* in_sizes, int n_in,
                              void* d_out, int out_size, void* d_ws, size_t ws_size,
                              hipStream_t stream) {
    const float* gt  = (const float*)d_in[0];
    const float* gen = (const float*)d_in[1];
    short* bt        = (short*)d_ws;               // 2 x 512 KB B-frags
    float* out       = (float*)d_out;

    cd_prep<<<128, 512, 0, stream>>>(gt, gen, bt, out);
    dim3 grid(NBLK, 2);                            // 256 x 2 = 512 blocks
    cd_main<<<grid, 512, 0, stream>>>(gt, gen, bt, out);
}

// Round 15
// 80.259 us; speedup vs baseline: 1.1296x; 1.0264x over previous
//
#include <hip/hip_runtime.h>
#include <float.h>

// Chamfer distance, fp32, N=M=16384 — MFMA 32x32, LDS-chunk sweep (R15).
//
// d(q,t) = u.t + |t|^2 + |q|^2, u=-2q, K=4 dot -> matrix cores via 2-level
// bf16 split, full product expansion in K=14 of 16 (absmax 0.0, R7-R14):
//   k:      0..2     3..5     6..7+8   9..11    12 13
//   A:    uh(xyz)  ul(xyz)  uh(xyz)  ul(xyz)    1  1
//   B:    th(xyz)  th(xyz)  tl(xyz)  tl(xyz)   wh wl
//
// R14 closed the null ledger on the global->register sweep: occupancy x2,
// min3, depth-1/depth-2 pipelines, launch merge, traffic halving — all null
// at ~34us vs ~10us pipe floor. Every variant read B from L2 (268MB at
// ~200cy). R15 transposes the decomposition: block = {512 queries (64/wave),
// ONE 2048-target chunk staged once into 64KB LDS}. Grid 32 x (8 tc x 2 dir)
// = 512 blocks, 2/CU, 16 waves/CU (TLP unchanged). Inner loop: 2
// ds_read_b128 + 4 MFMA + 32 v_min3 (mix unchanged); L2 traffic 268MB ->
// 16MB, latency ~200cy -> ~120cy LDS (deeply pipelined). Cross-block min
// via deterministic part2[dir][tc][q] (1MB) + finish kernel (|q|^2 added
// there; partials may be negative, no atomics in the min path).
// Discriminates: L2-bound -> cd_main ~10-16us (total ~60); invariant ~34
// -> memory path exonerated, declare next round.
//
// Layouts (guide §3, m74/m101-verified for 32x32):
//   A (32r x 16k): row = lane&31, k = 8*(lane>>5)+j
//   B (16k x 32c): col = lane&31, k = 8*(lane>>5)+j
//   D: col = lane&31, row = (reg&3) + 8*(reg>>2) + 4*(lane>>5)

#define NPTS 16384
constexpr int QPB   = 512;                // queries per block (64 per wave)
constexpr int NQB   = NPTS / QPB;         // 32 query-blocks per direction
constexpr int NFRAG = NPTS / 32;          // 512 B-frags per point set
constexpr int FPC   = 64;                 // frags per chunk (64KB LDS)
constexpr int NTC   = NFRAG / FPC;        // 8 target chunks
constexpr int FRAG_SHORTS = 512;          // 64 lanes x 8 bf16 = 1KB per frag
constexpr int SET_SHORTS  = NFRAG * FRAG_SHORTS;   // 512 KB per set

typedef float f32x16 __attribute__((ext_vector_type(16)));
typedef short bf16x8 __attribute__((ext_vector_type(8)));

__device__ inline ushort bf16rne(float f) {
    uint u = __float_as_uint(f);
    u += 0x7fff + ((u >> 16) & 1);        // round-to-nearest-even
    return (ushort)(u >> 16);
}
__device__ inline float bf2f(ushort h) { return __uint_as_float(((uint)h) << 16); }

// Split both point sets into B-fragment layout: bt[set][frag][lane][8 bf16].
// Also zeroes the output accumulator for cd_finish's atomic adds.
__global__ __launch_bounds__(512) void cd_prep(const float* __restrict__ gt,
                                               const float* __restrict__ gen,
                                               short* __restrict__ bt,
                                               float* __restrict__ out) {
    if (blockIdx.x == 0 && threadIdx.x == 0) out[0] = 0.0f;

    const int t   = blockIdx.x * 512 + threadIdx.x;   // 0..65535
    const int set = t >> 15;                          // 0: gt, 1: gen
    const int rem = t & 32767;
    const int h   = rem >> 14;                        // k-group 0/1
    const int p   = rem & (NPTS - 1);                 // point index
    const float* __restrict__ src = set ? gen : gt;

    const float x = src[3 * p + 0], y = src[3 * p + 1], z = src[3 * p + 2];
    const ushort hx = bf16rne(x), hy = bf16rne(y), hz = bf16rne(z);
    const ushort lx = bf16rne(x - bf2f(hx));
    const ushort ly = bf16rne(y - bf2f(hy));
    const ushort lz = bf16rne(z - bf2f(hz));
    const float w = fmaf(x, x, fmaf(y, y, z * z));
    const ushort wh = bf16rne(w), wl = bf16rne(w - bf2f(wh));

    bf16x8 v;
    if (h == 0)
        v = (bf16x8){(short)hx, (short)hy, (short)hz, (short)hx,
                     (short)hy, (short)hz, (short)lx, (short)ly};
    else
        v = (bf16x8){(short)lz, (short)lx, (short)ly, (short)lz,
                     (short)wh, (short)wl, (short)0, (short)0};
    *(bf16x8*)(bt + set * SET_SHORTS + (p >> 5) * FRAG_SHORTS
               + (h * 32 + (p & 31)) * 8) = v;
}

__global__ __launch_bounds__(512, 2) void cd_main(const float* __restrict__ gt,
                                                  const float* __restrict__ gen,
                                                  const short* __restrict__ bt,
                                                  float* __restrict__ part2) {
    const int tc  = blockIdx.y & (NTC - 1);        // target chunk 0..7
    const int dir = blockIdx.y >> 3;               // 0: gt->gen, 1: gen->gt
    const float* __restrict__ Q = dir ? gen : gt;
    const short* __restrict__ BT = bt + (dir ? 0 : SET_SHORTS)   // opposite set
                                 + tc * FPC * FRAG_SHORTS;

    __shared__ short FRsh[FPC * FRAG_SHORTS];      // 64 KB: this block's chunk

    const int tid  = threadIdx.x;
    const int lane = tid & 63;
    const int wave = __builtin_amdgcn_readfirstlane(tid >> 6);

    // ---- Stage the chunk once: 64KB linear copy, 8 x 16B per thread. ----
    #pragma unroll
    for (int k = 0; k < 8; ++k) {
        const int idx = k * 512 + tid;             // 0..4095 (16B units)
        ((bf16x8*)FRsh)[idx] = ((const bf16x8*)BT)[idx];
    }

    // ---- 2 A-frags per wave (each wave owns 64 DISTINCT queries). ----
    const int arow = lane & 31, kg = lane >> 5;
    const int qw = blockIdx.x * QPB + wave * 64;   // this wave's query base
    bf16x8 a[2];
    #pragma unroll
    for (int f = 0; f < 2; ++f) {
        const int q = qw + f * 32 + arow;
        const float x = Q[3 * q + 0], y = Q[3 * q + 1], z = Q[3 * q + 2];
        const float ux = -2.f * x, uy = -2.f * y, uz = -2.f * z;
        const ushort hx = bf16rne(ux), hy = bf16rne(uy), hz = bf16rne(uz);
        const ushort lx = bf16rne(ux - bf2f(hx));
        const ushort ly = bf16rne(uy - bf2f(hy));
        const ushort lz = bf16rne(uz - bf2f(hz));
        if (kg == 0)
            a[f] = (bf16x8){(short)hx, (short)hy, (short)hz, (short)lx,
                            (short)ly, (short)lz, (short)hx, (short)hy};
        else
            a[f] = (bf16x8){(short)hz, (short)lx, (short)ly, (short)lz,
                            (short)0x3f80, (short)0x3f80, (short)0, (short)0};
    }

    f32x16 mm0 = (f32x16)(FLT_MAX), mm1 = (f32x16)(FLT_MAX);
    const f32x16 zc = (f32x16)(0.f);

    __syncthreads();                               // chunk staged

    // ---- Sweep the 64 LDS frags, 2 per step, min3-merged. ----
    const short* rb = FRsh + lane * 8;
    for (int f2 = 0; f2 < FPC; f2 += 2) {
        const bf16x8 b0 = *(const bf16x8*)(rb + f2 * FRAG_SHORTS);
        const bf16x8 b1 = *(const bf16x8*)(rb + (f2 + 1) * FRAG_SHORTS);
        const f32x16 d00 = __builtin_amdgcn_mfma_f32_32x32x16_bf16(a[0], b0, zc, 0, 0, 0);
        const f32x16 d01 = __builtin_amdgcn_mfma_f32_32x32x16_bf16(a[0], b1, zc, 0, 0, 0);
        #pragma unroll
        for (int i = 0; i < 16; ++i)
            mm0[i] = fminf(fminf(d00[i], d01[i]), mm0[i]);   // -> v_min3_f32
        const f32x16 d10 = __builtin_amdgcn_mfma_f32_32x32x16_bf16(a[1], b0, zc, 0, 0, 0);
        const f32x16 d11 = __builtin_amdgcn_mfma_f32_32x32x16_bf16(a[1], b1, zc, 0, 0, 0);
        #pragma unroll
        for (int i = 0; i < 16; ++i)
            mm1[i] = fminf(fminf(d10[i], d11[i]), mm1[i]);
    }

    // ---- Cross-lane min over the 32 target-cols; write partials direct. ----
    float* pd = part2 + (size_t)blockIdx.y * NPTS + qw;   // [dir*8+tc][q]
    #pragma unroll
    for (int i = 0; i < 16; ++i) {
        float v0 = mm0[i], v1 = mm1[i];
        #pragma unroll
        for (int off = 1; off <= 16; off <<= 1) {
            v0 = fminf(v0, __shfl_xor(v0, off, 64));
            v1 = fminf(v1, __shfl_xor(v1, off, 64));
        }
        const int row = (i & 3) + 8 * (i >> 2) + 4 * kg;
        if ((lane & 31) == 0) {
            pd[row]      = v0;                     // frag 0: query qw+row
            pd[32 + row] = v1;                     // frag 1: query qw+32+row
        }
    }
}

// min over the 8 chunk-partials, add |q|^2, global sum.
__global__ __launch_bounds__(512) void cd_finish(const float* __restrict__ gt,
                                                 const float* __restrict__ gen,
                                                 const float* __restrict__ part2,
                                                 float* __restrict__ out) {
    const int t   = blockIdx.x * 512 + threadIdx.x;   // 0..32767
    const int dir = t >> 14;
    const int q   = t & (NPTS - 1);
    const float* __restrict__ Q = dir ? gen : gt;

    float m = FLT_MAX;
    #pragma unroll
    for (int tc = 0; tc < NTC; ++tc)
        m = fminf(m, part2[(size_t)(dir * NTC + tc) * NPTS + q]);
    const float x = Q[3 * q + 0], y = Q[3 * q + 1], z = Q[3 * q + 2];
    float v = m + fmaf(x, x, fmaf(y, y, z * z));

    #pragma unroll
    for (int off = 32; off > 0; off >>= 1) v += __shfl_down(v, off, 64);
    __shared__ float ws[8];
    const int lane = threadIdx.x & 63, w = threadIdx.x >> 6;
    if (lane == 0) ws[w] = v;
    __syncthreads();
    if (threadIdx.x == 0) {
        float s = 0.0f;
        #pragma unroll
        for (int i = 0; i < 8; ++i) s += ws[i];
        atomicAdd(out, s * (1.0f / (float)NPTS));
    }
}

extern "C" void kernel_launch(void* const* d_in, const int* in_sizes, int n_in,
                              void* d_out, int out_size, void* d_ws, size_t ws_size,
                              hipStream_t stream) {
    const float* gt  = (const float*)d_in[0];
    const float* gen = (const float*)d_in[1];
    short* bt        = (short*)d_ws;                            // 2 x 512 KB
    float* part2     = (float*)((short*)d_ws + 2 * SET_SHORTS); // 16 x 16384 f32
    float* out       = (float*)d_out;

    cd_prep<<<128, 512, 0, stream>>>(gt, gen, bt, out);
    dim3 grid(NQB, NTC * 2);                       // 32 x 16 = 512 blocks
    cd_main<<<grid, 512, 0, stream>>>(gt, gen, bt, part2);
    cd_finish<<<64, 512, 0, stream>>>(gt, gen, part2, out);
}